// Round 7
// baseline (213.806 us; speedup 1.0000x reference)
//
#include <hip/hip_runtime.h>

// Problem constants
#define N_NODES 25000
#define N_EDGES 200000
// MUL=16, NUM_RADIAL=8, HIDDEN=64, WNUMEL=1024
// PATH_ALPHA=1/sqrt(32), INV_SQRT3=1/sqrt(3), scales folded into B-fragments.

constexpr int ET = 32;        // edges per tile
constexpr int NTILES = 6250;  // 200000/32
constexpr int GRID = 512;     // persistent grid: 2 blocks/CU resident
constexpr int PL = ET * 17;   // xch plane stride in floats (544)
constexpr int CTS = 36;       // transposed coef row stride in floats (16B-aligned rows)

typedef __attribute__((ext_vector_type(8))) _Float16 half8;  // 8 f16 (4 VGPR)
typedef __attribute__((ext_vector_type(4))) _Float16 half4;  // 4 f16 (8B)
typedef __attribute__((ext_vector_type(4))) float float4v;   // 4 fp32

// Async global->LDS (no dest VGPRs; global addr is per-lane, LDS dest = base + lane*size).
__device__ __forceinline__ void gl_lds16(const void* g, void* l) {
    __builtin_amdgcn_global_load_lds((const __attribute__((address_space(1))) void*)g,
                                     (__attribute__((address_space(3))) void*)l, 16, 0, 0);
}
__device__ __forceinline__ void gl_lds4(const void* g, void* l) {
    __builtin_amdgcn_global_load_lds((const __attribute__((address_space(1))) void*)g,
                                     (__attribute__((address_space(3))) void*)l, 4, 0, 0);
}

// ---------------- fused kernel: sc + edge messages, atomics into zeroed out ----------------
// 512 threads, 8 waves. Wave w: q = w>>1 (W2 column chunk 0..3), uh = w&1 (u-half).
// Math: au[e][v] = sum_c h[e][c] * W2[c][q*256+u*16+v]  (pure MFMA, unscaled h),
// then C[e][v] += coef[e][u] * au[e][v]  (f32 FMA on the D-side).
// D-side lane layout: lane holds rows quad*4+r, col qm -> coef must be indexed by
// edge = mt*16+quad*4+r. Coef planes stored TRANSPOSED [u][e] so one ds_read_b128
// fetches the 4 row-coefs (round-6 bug was indexing coef by qm here).
//   chunk 0: coef = xj0*sh0 | chunk 1: coef = b1 (INV_SQRT3 in bfr) | chunk 2: coef = xj0
//   chunk 3: coef = xj1[.,k]*sh0, k=0..2 (3 accumulator sets, ONE au evaluation)
// Per tile: [phase2: cf/h16 from LDS buffers[p]] B1 [issue async stage of T+1;
// phase3: MFMA+contract+xch] B2(drains stage under MFMA) [combine: atomics] -> loop.
__global__ __launch_bounds__(512, 4) void fused_kernel(
    const float* __restrict__ x, const float* __restrict__ edge_attr,
    const float* __restrict__ edge_length, const int* __restrict__ edge_src,
    const int* __restrict__ edge_dst, const float* __restrict__ W1,
    const float* __restrict__ W2, const float* __restrict__ L0,
    const float* __restrict__ L1, float* __restrict__ out) {

    const int t = threadIdx.x;
    const int w = t >> 6;             // wave id 0..7
    const int lane = t & 63;
    const int q = w >> 1;             // W2 column chunk 0..3
    const int uh = w & 1;             // u-half
    const int qm = t & 15;            // MFMA m/n index
    const int quad = (t >> 4) & 3;    // lane quad within wave
    const int eL = t >> 4;            // phase2: edge within tile (0..31)
    const int uL = t & 15;            // phase2: u within edge (0..15)

    __shared__ __attribute__((aligned(16))) _Float16 lds_h16[ET * 72];   // h f16, stride 72
    __shared__ __attribute__((aligned(16))) float lds_cfT[3][16][CTS];   // coef planes 0..2, [u][e]
    __shared__ __attribute__((aligned(16))) float lds_cf3T[3][16][CTS];  // chunk3 coefs k=0..2, [u][e]
    __shared__ __attribute__((aligned(16))) float lds_xch[12 * PL];      // term exchange
    __shared__ __attribute__((aligned(16))) float lds_w1t[64 * 8];       // W1^T [c][r]
    __shared__ __attribute__((aligned(16))) float l0[256], l1[256];      // L0, L1
    __shared__ __attribute__((aligned(16))) float lds_xj[2][ET * 64];    // dbuf x[src], LINEAR stride 64
    __shared__ __attribute__((aligned(16))) float lds_ea[2][ET * 4];     // dbuf edge_attr
    __shared__ __attribute__((aligned(16))) float lds_len[2][ET];
    __shared__ __attribute__((aligned(16))) int   lds_dst[2][ET];
    __shared__ __attribute__((aligned(16))) int   lds_srcb[2][ET];       // srcb[p] = src(T+1)

    // ---- persistent B fragments: W2 chunk `q`, u-half `uh`, pre-scaled f16 ----
    half8 bfr[8][2];
    {
        float scale = 0.0220970869f;                  // (1/sqrt(64)) * (1/sqrt(32))
        if (q == 1) scale *= 0.5773502692f;           // INV_SQRT3 folded
        const int kr = quad * 8;
        #pragma unroll
        for (int up = 0; up < 8; ++up) {
            const int col = q * 256 + (uh * 8 + up) * 16 + qm;
            #pragma unroll
            for (int kf = 0; kf < 2; ++kf) {
                half8 f;
                #pragma unroll
                for (int j = 0; j < 8; ++j) {
                    const int k = kf * 32 + kr + j;
                    f[j] = (_Float16)(W2[k * 1024 + col] * scale);
                }
                bfr[up][kf] = f;
            }
        }
    }
    // W1 -> LDS transposed [c][r]; L0/L1 -> LDS
    lds_w1t[(t & 63) * 8 + (t >> 6)] = W1[t];
    if (t < 256) l0[t] = L0[t];
    else         l1[t - 256] = L1[t - 256];

    // ---- prologue: async-stage tile T into buffers[0]; srcb[0] = src(T+1) ----
    int T = blockIdx.x;
    if (w == 0 && lane < ET) gl_lds4(edge_src + T * ET + lane, &lds_srcb[1][0]);
    __syncthreads();   // srcb[1]=src(T) visible; w1t/l0/l1 visible
    {
        const int e4 = (w << 2) + (lane >> 4);
        const int src = lds_srcb[1][e4];
        gl_lds16(x + src * 64 + (lane & 15) * 4, &lds_xj[0][w * 256]);
    }
    if (w == 0 && lane < ET) gl_lds16(edge_attr + 4 * (T * ET + lane), &lds_ea[0][0]);
    if (w == 1 && lane < ET) gl_lds4(edge_length + T * ET + lane, &lds_len[0][0]);
    if (w == 2 && lane < ET) gl_lds4(edge_dst + T * ET + lane, &lds_dst[0][0]);
    if (w == 3 && lane < ET) {
        const int Tn = (T + GRID < NTILES) ? T + GRID : T;
        gl_lds4(edge_src + Tn * ET + lane, &lds_srcb[0][0]);
    }

    // ---- self-connection under the stage latency: shuffle matvec + atomics ----
    {
        const bool is0 = lane < 16;
        const int qq = lane - 16;
        const int v = is0 ? lane : qq / 3;
        const int k = is0 ? 0 : qq - 3 * v;
        const float* mat = is0 ? l0 : l1;
        for (int n = blockIdx.x * 8 + w; n < N_NODES; n += GRID * 8) {
            const float xv = x[n * 64 + lane];
            float s = 0.f;
            #pragma unroll
            for (int u = 0; u < 16; ++u) {
                const int sel = is0 ? u : 16 + 3 * u + k;
                s = fmaf(__shfl(xv, sel), mat[u * 16 + v], s);
            }
            atomicAdd(out + n * 64 + lane, 0.25f * s);   // 1/sqrt(MUL)
        }
    }
    __syncthreads();   // drains prologue stage (+sc atomics): buffers[0] ready

    int p = 0;
    while (true) {
        // ---- phase 2: transposed coef (f32) + h16 from buffers[p] (thread = (eL, uL)) ----
        {
            const float sh0 = lds_ea[p][eL * 4 + 0];
            const float s1x = lds_ea[p][eL * 4 + 1];
            const float s1y = lds_ea[p][eL * 4 + 2];
            const float s1z = lds_ea[p][eL * 4 + 3];
            const float* xr = &lds_xj[p][eL * 64];
            const float xj0v = xr[uL];
            const float x0 = xr[16 + 3 * uL];
            const float x1 = xr[17 + 3 * uL];
            const float x2 = xr[18 + 3 * uL];
            lds_cfT[0][uL][eL] = xj0v * sh0;
            lds_cfT[1][uL][eL] = fmaf(x0, s1x, fmaf(x1, s1y, x2 * s1z));
            lds_cfT[2][uL][eL] = xj0v;
            lds_cf3T[0][uL][eL] = x0 * sh0;
            lds_cf3T[1][uL][eL] = x1 * sh0;
            lds_cf3T[2][uL][eL] = x2 * sh0;
            // h = silu(radial @ W1 / sqrt(8)) for (e=eL, c = uL*4 .. +3), stored f16
            const int c0 = uL * 4;
            const float len = lds_len[p][eL];
            float rad[8];
            #pragma unroll
            for (int r = 0; r < 8; ++r) {
                const float d = len - 0.7142857143f * (float)r;
                rad[r] = __expf(-0.5f * d * d);
            }
            half4 hv;
            #pragma unroll
            for (int i = 0; i < 4; ++i) {
                const float4v wA = *(const float4v*)(&lds_w1t[(c0 + i) * 8]);
                const float4v wB = *(const float4v*)(&lds_w1t[(c0 + i) * 8 + 4]);
                float s = rad[0] * wA[0] + rad[1] * wA[1] + rad[2] * wA[2] + rad[3] * wA[3]
                        + rad[4] * wB[0] + rad[5] * wB[1] + rad[6] * wB[2] + rad[7] * wB[3];
                s *= 0.3535533906f;
                hv[i] = (_Float16)(s / (1.f + __expf(-s)));
            }
            *(half4*)(&lds_h16[eL * 72 + c0]) = hv;
        }

        __syncthreads();   // B1: cf/h16 visible

        // ---- issue async stage of tile T+1 into buffers[p^1] (zero registers) ----
        const int Tn = T + GRID;
        if (Tn < NTILES) {
            const int pn = p ^ 1;
            {
                const int e4 = (w << 2) + (lane >> 4);
                const int src = lds_srcb[p][e4];
                gl_lds16(x + src * 64 + (lane & 15) * 4, &lds_xj[pn][w * 256]);
            }
            if (w == 0 && lane < ET) gl_lds16(edge_attr + 4 * (Tn * ET + lane), &lds_ea[pn][0]);
            if (w == 1 && lane < ET) gl_lds4(edge_length + Tn * ET + lane, &lds_len[pn][0]);
            if (w == 2 && lane < ET) gl_lds4(edge_dst + Tn * ET + lane, &lds_dst[pn][0]);
            if (w == 3 && lane < ET) {
                const int T2 = (Tn + GRID < NTILES) ? Tn + GRID : Tn;
                gl_lds4(edge_src + T2 * ET + lane, &lds_srcb[pn][0]);
            }
        }

        // ---- phase 3: unscaled-h MFMA -> au; contract with per-ROW coef in f32 ----
        // au element r is edge mt*16+quad*4+r -> one b128 from [u][e] plane gives cr[r].
        half8 ah[2][2];
        #pragma unroll
        for (int mt = 0; mt < 2; ++mt)
            #pragma unroll
            for (int kf = 0; kf < 2; ++kf)
                ah[mt][kf] = *(const half8*)(&lds_h16[(mt * 16 + qm) * 72 + kf * 32 + quad * 8]);

        if (q < 3) {
            float4v C[2];
            C[0] = (float4v){0.f, 0.f, 0.f, 0.f};
            C[1] = (float4v){0.f, 0.f, 0.f, 0.f};
            #pragma unroll
            for (int up = 0; up < 8; ++up) {
                const int u = uh * 8 + up;
                #pragma unroll
                for (int mt = 0; mt < 2; ++mt) {
                    float4v au = __builtin_amdgcn_mfma_f32_16x16x32_f16(
                        ah[mt][0], bfr[up][0], (float4v){0.f, 0.f, 0.f, 0.f}, 0, 0, 0);
                    au = __builtin_amdgcn_mfma_f32_16x16x32_f16(
                        ah[mt][1], bfr[up][1], au, 0, 0, 0);
                    const float4v cr = *(const float4v*)(&lds_cfT[q][u][mt * 16 + quad * 4]);
                    C[mt] += au * cr;     // per-row coef (rows quad*4+r)
                }
            }
            float* xb = &lds_xch[(q * 2 + uh) * PL];
            #pragma unroll
            for (int mt = 0; mt < 2; ++mt)
                #pragma unroll
                for (int r = 0; r < 4; ++r)
                    xb[(mt * 16 + quad * 4 + r) * 17 + qm] = C[mt][r];
        } else {
            float4v C3[3][2];
            #pragma unroll
            for (int k = 0; k < 3; ++k) {
                C3[k][0] = (float4v){0.f, 0.f, 0.f, 0.f};
                C3[k][1] = (float4v){0.f, 0.f, 0.f, 0.f};
            }
            #pragma unroll
            for (int up = 0; up < 8; ++up) {
                const int u = uh * 8 + up;
                #pragma unroll
                for (int mt = 0; mt < 2; ++mt) {
                    float4v au = __builtin_amdgcn_mfma_f32_16x16x32_f16(
                        ah[mt][0], bfr[up][0], (float4v){0.f, 0.f, 0.f, 0.f}, 0, 0, 0);
                    au = __builtin_amdgcn_mfma_f32_16x16x32_f16(
                        ah[mt][1], bfr[up][1], au, 0, 0, 0);
                    #pragma unroll
                    for (int k = 0; k < 3; ++k) {
                        const float4v ck = *(const float4v*)(&lds_cf3T[k][u][mt * 16 + quad * 4]);
                        C3[k][mt] += au * ck;
                    }
                }
            }
            #pragma unroll
            for (int k = 0; k < 3; ++k) {
                float* xb = &lds_xch[(6 + uh * 3 + k) * PL];
                #pragma unroll
                for (int mt = 0; mt < 2; ++mt)
                    #pragma unroll
                    for (int r = 0; r < 4; ++r)
                        xb[(mt * 16 + quad * 4 + r) * 17 + qm] = C3[k][mt][r];
            }
        }

        __syncthreads();   // B2: xch visible; stage of T+1 drained (hidden under MFMA)

        // ---- combine: 4 output elems per thread, ONE atomic each ----
        #pragma unroll
        for (int i = 0; i < 4; ++i) {
            const int idx = t + 512 * i;          // 2048 = 32 edges x 64 elems
            const int e = idx >> 6, j = idx & 63;
            float val;
            if (j < 16) {
                val = (lds_xch[0 * PL + e * 17 + j] + lds_xch[1 * PL + e * 17 + j])
                    + (lds_xch[2 * PL + e * 17 + j] + lds_xch[3 * PL + e * 17 + j]);
            } else {
                const int qj = j - 16, v = qj / 3, k = qj - 3 * v;
                const float s2 = lds_xch[4 * PL + e * 17 + v] + lds_xch[5 * PL + e * 17 + v];
                const float s3 = lds_xch[(6 + k) * PL + e * 17 + v]
                               + lds_xch[(9 + k) * PL + e * 17 + v];
                val = fmaf(s2, lds_ea[p][e * 4 + 1 + k], s3);
            }
            atomicAdd(out + lds_dst[p][e] * 64 + j, val);
        }

        if (Tn >= NTILES) break;
        T = Tn;
        p ^= 1;
        // next phase 2 reads buffers[p^1] (drained at B2); atomics overlap next phase 2,
        // drained at next B1.
    }
}

extern "C" void kernel_launch(void* const* d_in, const int* in_sizes, int n_in,
                              void* d_out, int out_size, void* d_ws, size_t ws_size,
                              hipStream_t stream) {
    const float* x           = (const float*)d_in[0];
    const float* edge_attr   = (const float*)d_in[1];
    const float* edge_length = (const float*)d_in[2];
    const int*   edge_src    = (const int*)d_in[3];
    const int*   edge_dst    = (const int*)d_in[4];
    const float* W1          = (const float*)d_in[5];
    const float* W2          = (const float*)d_in[6];
    const float* L0          = (const float*)d_in[7];
    const float* L1          = (const float*)d_in[8];
    float* out = (float*)d_out;

    hipMemsetAsync(out, 0, (size_t)N_NODES * 64 * sizeof(float), stream);
    fused_kernel<<<GRID, 512, 0, stream>>>(
        x, edge_attr, edge_length, edge_src, edge_dst, W1, W2, L0, L1, out);
}

// Round 8
// 181.534 us; speedup vs baseline: 1.1778x; 1.1778x over previous
//
#include <hip/hip_runtime.h>

// Problem constants
#define N_NODES 25000
#define N_EDGES 200000
// MUL=16, NUM_RADIAL=8, HIDDEN=64, WNUMEL=1024
// PATH_ALPHA=1/sqrt(32), INV_SQRT3=1/sqrt(3), scales folded into B-fragments.

constexpr int ET = 32;        // edges per tile
constexpr int NTILES = 6250;  // 200000/32
constexpr int GRID = 512;     // persistent grid: 2 blocks/CU resident
constexpr int XPS = 584;      // xch plane stride in floats (584%32==8 -> bank-spread planes)
constexpr int XRS = 18;       // xch row stride (2-way-free writes)
constexpr int CTS = 36;       // transposed coef row stride in floats (16B-aligned rows)

typedef __attribute__((ext_vector_type(8))) _Float16 half8;  // 8 f16 (4 VGPR)
typedef __attribute__((ext_vector_type(4))) _Float16 half4;  // 4 f16 (8B)
typedef __attribute__((ext_vector_type(4))) float float4v;   // 4 fp32

// Async global->LDS (no dest VGPRs; global addr is per-lane, LDS dest = base + lane*size).
__device__ __forceinline__ void gl_lds16(const void* g, void* l) {
    __builtin_amdgcn_global_load_lds((const __attribute__((address_space(1))) void*)g,
                                     (__attribute__((address_space(3))) void*)l, 16, 0, 0);
}
__device__ __forceinline__ void gl_lds4(const void* g, void* l) {
    __builtin_amdgcn_global_load_lds((const __attribute__((address_space(1))) void*)g,
                                     (__attribute__((address_space(3))) void*)l, 4, 0, 0);
}

// ---------------- fused kernel: sc + edge messages, atomics into zeroed out ----------------
// 512 threads, 8 waves. Wave w: q = w>>1 (W2 column chunk 0..3), uh = w&1 (u-half).
// Math: au[e][v] = sum_c h[e][c] * W2[c][q*256+u*16+v]  (pure MFMA, unscaled h),
// then C[e][v] += coef[e][u] * au[e][v]  (f32 FMA, per-ROW coef: rows quad*4+r).
//   chunk 0: coef = xj0*sh0 | chunk 1: coef = b1 (INV_SQRT3 in bfr) | chunk 2: coef = xj0
//   chunk 3: coef = xj1[.,k]*sh0, k=0..2 (3 accumulator sets, ONE au evaluation)
// Triple-buffered staging, 2 tiles ahead:
//   segA(T): phase2 on slot p | B1 | segB(T): issue stage(T+2G)->slot p2, src(T+3G)->srcb[p];
//   phase3 -> xch | B2 (drains stage, ~2 segments of cover) | combine(T): atomics -> loop.
__global__ __launch_bounds__(512, 4) void fused_kernel(
    const float* __restrict__ x, const float* __restrict__ edge_attr,
    const float* __restrict__ edge_length, const int* __restrict__ edge_src,
    const int* __restrict__ edge_dst, const float* __restrict__ W1,
    const float* __restrict__ W2, const float* __restrict__ L0,
    const float* __restrict__ L1, float* __restrict__ out) {

    const int t = threadIdx.x;
    const int w = t >> 6;             // wave id 0..7
    const int lane = t & 63;
    const int q = w >> 1;             // W2 column chunk 0..3
    const int uh = w & 1;             // u-half
    const int qm = t & 15;            // MFMA m/n index
    const int quad = (t >> 4) & 3;    // lane quad within wave
    const int eL = t >> 4;            // phase2: edge within tile (0..31)
    const int uL = t & 15;            // phase2: raw u lane (0..15)
    const int uS = (uL + ((eL & 3) << 2)) & 15;   // swizzled u -> conflict-free xj reads

    __shared__ __attribute__((aligned(16))) _Float16 lds_h16[ET * 72];   // h f16, stride 72
    __shared__ __attribute__((aligned(16))) float lds_cfT[3][16][CTS];   // coef planes 0..2, [u][e]
    __shared__ __attribute__((aligned(16))) float lds_cf3T[3][16][CTS];  // chunk3 coefs k=0..2, [u][e]
    __shared__ __attribute__((aligned(16))) float lds_xch[12 * XPS];     // term exchange
    __shared__ __attribute__((aligned(16))) float lds_w1t[64 * 8];       // W1^T [c][r]
    __shared__ __attribute__((aligned(16))) float l0[256], l1[256];      // L0, L1
    __shared__ __attribute__((aligned(16))) float lds_xj[3][ET * 64];    // 3-buf x[src], LINEAR stride 64
    __shared__ __attribute__((aligned(16))) float lds_ea[3][ET * 4];     // 3-buf edge_attr
    __shared__ __attribute__((aligned(16))) float lds_len[3][ET];
    __shared__ __attribute__((aligned(16))) int   lds_dst[3][ET];
    __shared__ __attribute__((aligned(16))) int   lds_srcb[3][ET];       // src indices, see chain

    // ---- persistent B fragments: W2 chunk `q`, u-half `uh`, pre-scaled f16 ----
    half8 bfr[8][2];
    {
        float scale = 0.0220970869f;                  // (1/sqrt(64)) * (1/sqrt(32))
        if (q == 1) scale *= 0.5773502692f;           // INV_SQRT3 folded
        const int kr = quad * 8;
        #pragma unroll
        for (int up = 0; up < 8; ++up) {
            const int col = q * 256 + (uh * 8 + up) * 16 + qm;
            #pragma unroll
            for (int kf = 0; kf < 2; ++kf) {
                half8 f;
                #pragma unroll
                for (int j = 0; j < 8; ++j) {
                    const int k = kf * 32 + kr + j;
                    f[j] = (_Float16)(W2[k * 1024 + col] * scale);
                }
                bfr[up][kf] = f;
            }
        }
    }
    // W1 -> LDS transposed [c][r]; L0/L1 -> LDS
    lds_w1t[(t & 63) * 8 + (t >> 6)] = W1[t];
    if (t < 256) l0[t] = L0[t];
    else         l1[t - 256] = L1[t - 256];

    // ---- prologue: srcb for T0/T1/T2; then stage T0->slot0, T1->slot1 ----
    int T = blockIdx.x;                 // tile being processed; slot p
    // T0=T, T1=T+GRID, T2=T+2*GRID all < 6250 for T<512.
    if (w == 0 && lane < ET) gl_lds4(edge_src + T * ET + lane, &lds_srcb[0][0]);
    if (w == 1 && lane < ET) gl_lds4(edge_src + (T + GRID) * ET + lane, &lds_srcb[1][0]);
    if (w == 2 && lane < ET) gl_lds4(edge_src + (T + 2 * GRID) * ET + lane, &lds_srcb[2][0]);
    __syncthreads();   // srcb[0..2] visible; w1t/l0/l1 visible
    {
        const int e4 = (w << 2) + (lane >> 4);
        const int c4 = (lane & 15) * 4;
        gl_lds16(x + lds_srcb[0][e4] * 64 + c4, &lds_xj[0][w * 256]);
        gl_lds16(x + lds_srcb[1][e4] * 64 + c4, &lds_xj[1][w * 256]);
    }
    if (w == 0 && lane < ET) gl_lds16(edge_attr + 4 * (T * ET + lane), &lds_ea[0][0]);
    if (w == 1 && lane < ET) gl_lds4(edge_length + T * ET + lane, &lds_len[0][0]);
    if (w == 2 && lane < ET) gl_lds4(edge_dst + T * ET + lane, &lds_dst[0][0]);
    if (w == 3 && lane < ET) gl_lds16(edge_attr + 4 * ((T + GRID) * ET + lane), &lds_ea[1][0]);
    if (w == 4 && lane < ET) gl_lds4(edge_length + (T + GRID) * ET + lane, &lds_len[1][0]);
    if (w == 5 && lane < ET) gl_lds4(edge_dst + (T + GRID) * ET + lane, &lds_dst[1][0]);

    // ---- self-connection under the stage latency: shuffle matvec + atomics ----
    {
        const bool is0 = lane < 16;
        const int qq = lane - 16;
        const int v = is0 ? lane : qq / 3;
        const int k = is0 ? 0 : qq - 3 * v;
        const float* mat = is0 ? l0 : l1;
        for (int n = blockIdx.x * 8 + w; n < N_NODES; n += GRID * 8) {
            const float xv = x[n * 64 + lane];
            float s = 0.f;
            #pragma unroll
            for (int u = 0; u < 16; ++u) {
                const int sel = is0 ? u : 16 + 3 * u + k;
                s = fmaf(__shfl(xv, sel), mat[u * 16 + v], s);
            }
            atomicAdd(out + n * 64 + lane, 0.25f * s);   // 1/sqrt(MUL)
        }
    }
    __syncthreads();   // drains prologue stage: slots 0,1 ready

    int p = 0;
    while (true) {
        // ---- segA / phase 2: transposed coef (f32) + h16 from slot p (thread = (eL,uS)) ----
        {
            const float sh0 = lds_ea[p][eL * 4 + 0];
            const float s1x = lds_ea[p][eL * 4 + 1];
            const float s1y = lds_ea[p][eL * 4 + 2];
            const float s1z = lds_ea[p][eL * 4 + 3];
            const float* xr = &lds_xj[p][eL * 64];
            const float xj0v = xr[uS];
            const float x0 = xr[16 + 3 * uS];
            const float x1 = xr[17 + 3 * uS];
            const float x2 = xr[18 + 3 * uS];
            lds_cfT[0][uS][eL] = xj0v * sh0;
            lds_cfT[1][uS][eL] = fmaf(x0, s1x, fmaf(x1, s1y, x2 * s1z));
            lds_cfT[2][uS][eL] = xj0v;
            lds_cf3T[0][uS][eL] = x0 * sh0;
            lds_cf3T[1][uS][eL] = x1 * sh0;
            lds_cf3T[2][uS][eL] = x2 * sh0;
            // h = silu(radial @ W1 / sqrt(8)) for (e=eL, c = uS*4 .. +3), stored f16
            const int c0 = uS * 4;
            const float len = lds_len[p][eL];
            float rad[8];
            #pragma unroll
            for (int r = 0; r < 8; ++r) {
                const float d = len - 0.7142857143f * (float)r;
                rad[r] = __expf(-0.5f * d * d);
            }
            half4 hv;
            #pragma unroll
            for (int i = 0; i < 4; ++i) {
                const float4v wA = *(const float4v*)(&lds_w1t[(c0 + i) * 8]);
                const float4v wB = *(const float4v*)(&lds_w1t[(c0 + i) * 8 + 4]);
                float s = rad[0] * wA[0] + rad[1] * wA[1] + rad[2] * wA[2] + rad[3] * wA[3]
                        + rad[4] * wB[0] + rad[5] * wB[1] + rad[6] * wB[2] + rad[7] * wB[3];
                s *= 0.3535533906f;
                hv[i] = (_Float16)(s / (1.f + __expf(-s)));
            }
            *(half4*)(&lds_h16[eL * 72 + c0]) = hv;
        }

        __syncthreads();   // B1: cf/h16 visible

        // ---- segB: issue async stage of T+2G into slot p2; src(T+3G) into srcb[p] ----
        const int T2 = T + 2 * GRID;
        if (T2 < NTILES) {
            const int p2 = (p + 2) % 3;
            {
                const int e4 = (w << 2) + (lane >> 4);
                const int src = lds_srcb[p2][e4];        // src(T+2G), loaded last iter
                gl_lds16(x + src * 64 + (lane & 15) * 4, &lds_xj[p2][w * 256]);
            }
            if (w == 0 && lane < ET) gl_lds16(edge_attr + 4 * (T2 * ET + lane), &lds_ea[p2][0]);
            if (w == 1 && lane < ET) gl_lds4(edge_length + T2 * ET + lane, &lds_len[p2][0]);
            if (w == 2 && lane < ET) gl_lds4(edge_dst + T2 * ET + lane, &lds_dst[p2][0]);
            if (w == 3 && lane < ET) {
                const int e3 = min((T + 3 * GRID) * ET + lane, N_EDGES - 1);
                gl_lds4(edge_src + e3, &lds_srcb[p][0]);  // src(T+3G) -> slot of T+3G
            }
        }

        // ---- phase 3: unscaled-h MFMA -> au; contract with per-ROW coef (mt-split) ----
        if (q < 3) {
            #pragma unroll
            for (int mt = 0; mt < 2; ++mt) {
                const half8 a0 = *(const half8*)(&lds_h16[(mt * 16 + qm) * 72 + quad * 8]);
                const half8 a1 = *(const half8*)(&lds_h16[(mt * 16 + qm) * 72 + 32 + quad * 8]);
                float4v C = (float4v){0.f, 0.f, 0.f, 0.f};
                #pragma unroll
                for (int up = 0; up < 8; ++up) {
                    const int u = uh * 8 + up;
                    float4v au = __builtin_amdgcn_mfma_f32_16x16x32_f16(
                        a0, bfr[up][0], (float4v){0.f, 0.f, 0.f, 0.f}, 0, 0, 0);
                    au = __builtin_amdgcn_mfma_f32_16x16x32_f16(a1, bfr[up][1], au, 0, 0, 0);
                    const float4v cr = *(const float4v*)(&lds_cfT[q][u][mt * 16 + quad * 4]);
                    C += au * cr;     // per-row coef (rows quad*4+r)
                }
                float* xb = &lds_xch[(q * 2 + uh) * XPS];
                #pragma unroll
                for (int r = 0; r < 4; ++r)
                    xb[(mt * 16 + quad * 4 + r) * XRS + qm] = C[r];
            }
        } else {
            #pragma unroll
            for (int mt = 0; mt < 2; ++mt) {
                const half8 a0 = *(const half8*)(&lds_h16[(mt * 16 + qm) * 72 + quad * 8]);
                const half8 a1 = *(const half8*)(&lds_h16[(mt * 16 + qm) * 72 + 32 + quad * 8]);
                float4v C3[3];
                C3[0] = (float4v){0.f, 0.f, 0.f, 0.f};
                C3[1] = (float4v){0.f, 0.f, 0.f, 0.f};
                C3[2] = (float4v){0.f, 0.f, 0.f, 0.f};
                #pragma unroll
                for (int up = 0; up < 8; ++up) {
                    const int u = uh * 8 + up;
                    float4v au = __builtin_amdgcn_mfma_f32_16x16x32_f16(
                        a0, bfr[up][0], (float4v){0.f, 0.f, 0.f, 0.f}, 0, 0, 0);
                    au = __builtin_amdgcn_mfma_f32_16x16x32_f16(a1, bfr[up][1], au, 0, 0, 0);
                    #pragma unroll
                    for (int k = 0; k < 3; ++k) {
                        const float4v ck = *(const float4v*)(&lds_cf3T[k][u][mt * 16 + quad * 4]);
                        C3[k] += au * ck;
                    }
                }
                #pragma unroll
                for (int k = 0; k < 3; ++k) {
                    float* xb = &lds_xch[(6 + uh * 3 + k) * XPS];
                    #pragma unroll
                    for (int r = 0; r < 4; ++r)
                        xb[(mt * 16 + quad * 4 + r) * XRS + qm] = C3[k][r];
                }
            }
        }

        __syncthreads();   // B2: xch visible; stage of T+2G drained (2 segments of cover)

        // ---- combine: 4 output elems per thread, ONE atomic each ----
        #pragma unroll
        for (int i = 0; i < 4; ++i) {
            const int idx = t + 512 * i;          // 2048 = 32 edges x 64 elems
            const int e = idx >> 6, j = idx & 63;
            float val;
            if (j < 16) {
                val = (lds_xch[0 * XPS + e * XRS + j] + lds_xch[1 * XPS + e * XRS + j])
                    + (lds_xch[2 * XPS + e * XRS + j] + lds_xch[3 * XPS + e * XRS + j]);
            } else {
                const int qj = j - 16, v = qj / 3, k = qj - 3 * v;
                const float s2 = lds_xch[4 * XPS + e * XRS + v] + lds_xch[5 * XPS + e * XRS + v];
                const float s3 = lds_xch[(6 + k) * XPS + e * XRS + v]
                               + lds_xch[(9 + k) * XPS + e * XRS + v];
                val = fmaf(s2, lds_ea[p][e * 4 + 1 + k], s3);
            }
            atomicAdd(out + lds_dst[p][e] * 64 + j, val);
        }

        const int Tn = T + GRID;
        if (Tn >= NTILES) break;
        T = Tn;
        p = (p + 1) % 3;
        // next segA reads slot p (staged 2 iters ago, drained at its B2);
        // atomics issued here drain at next B1 (covered by phase2).
    }
}

extern "C" void kernel_launch(void* const* d_in, const int* in_sizes, int n_in,
                              void* d_out, int out_size, void* d_ws, size_t ws_size,
                              hipStream_t stream) {
    const float* x           = (const float*)d_in[0];
    const float* edge_attr   = (const float*)d_in[1];
    const float* edge_length = (const float*)d_in[2];
    const int*   edge_src    = (const int*)d_in[3];
    const int*   edge_dst    = (const int*)d_in[4];
    const float* W1          = (const float*)d_in[5];
    const float* W2          = (const float*)d_in[6];
    const float* L0          = (const float*)d_in[7];
    const float* L1          = (const float*)d_in[8];
    float* out = (float*)d_out;

    hipMemsetAsync(out, 0, (size_t)N_NODES * 64 * sizeof(float), stream);
    fused_kernel<<<GRID, 512, 0, stream>>>(
        x, edge_attr, edge_length, edge_src, edge_dst, W1, W2, L0, L1, out);
}

// Round 9
// 180.734 us; speedup vs baseline: 1.1830x; 1.0044x over previous
//
#include <hip/hip_runtime.h>

// Problem constants
#define N_NODES 25000
#define N_EDGES 200000
// MUL=16, NUM_RADIAL=8, HIDDEN=64, WNUMEL=1024
// PATH_ALPHA=1/sqrt(32), INV_SQRT3=1/sqrt(3), scales folded into B-fragments.

constexpr int ET = 32;        // edges per tile
constexpr int NTILES = 6250;  // 200000/32
constexpr int GRID = 512;     // persistent grid: 2 blocks/CU resident
constexpr int XPS = 584;      // xch plane stride in floats (584%32==8 -> bank-spread planes)
constexpr int XRS = 18;       // xch row stride (2-way-free writes)
constexpr int CTS = 36;       // transposed coef row stride in floats (16B-aligned rows)

typedef __attribute__((ext_vector_type(8))) _Float16 half8;  // 8 f16 (4 VGPR)
typedef __attribute__((ext_vector_type(4))) _Float16 half4;  // 4 f16 (8B)
typedef __attribute__((ext_vector_type(4))) float float4v;   // 4 fp32

// Async global->LDS (no dest VGPRs; global addr is per-lane, LDS dest = base + lane*size).
__device__ __forceinline__ void gl_lds16(const void* g, void* l) {
    __builtin_amdgcn_global_load_lds((const __attribute__((address_space(1))) void*)g,
                                     (__attribute__((address_space(3))) void*)l, 16, 0, 0);
}
__device__ __forceinline__ void gl_lds4(const void* g, void* l) {
    __builtin_amdgcn_global_load_lds((const __attribute__((address_space(1))) void*)g,
                                     (__attribute__((address_space(3))) void*)l, 4, 0, 0);
}

// LDS-visibility-only barrier: waits own LDS ops (lgkmcnt) then syncs. Does NOT
// drain vmcnt -> in-flight atomics and global_load_lds stages keep flying.
__device__ __forceinline__ void wg_barrier() {
    asm volatile("s_waitcnt lgkmcnt(0)" ::: "memory");
    __builtin_amdgcn_s_barrier();
    asm volatile("" ::: "memory");
}

// ---------------- fused kernel: sc + edge messages, atomics into zeroed out ----------------
// 512 threads, 8 waves. Wave w: q = w>>1 (W2 column chunk 0..3), uh = w&1 (u-half).
// Math: au[e][v] = sum_c h[e][c] * W2[c][q*256+u*16+v]  (pure MFMA, unscaled h),
// then C[e][v] += coef[e][u] * au[e][v]  (f32 FMA, per-ROW coef: rows quad*4+r).
//   chunk 0: coef = xj0*sh0 | chunk 1: coef = b1 (INV_SQRT3 in bfr) | chunk 2: coef = xj0
//   chunk 3: coef = xj1[.,k]*sh0, k=0..2 (3 accumulator sets, ONE au evaluation)
// Schedule (round 9): stage issue at TOP of segA -> drain at B2 has a full
// iteration of cover; B1 is lgkm-only so combine atomics drain at B2 under phase3.
//   segA(it): issue stage(T+2G)->xj[(p+2)%3]/meta[(m+2)&3], srcb(T+3G); phase2(slot p,m)
//   B1 (lgkm-only) | phase3: MFMA+contract -> xch | B2 (__syncthreads, vmcnt drain)
//   combine(meta m): atomics -> loop.
// Rings: xj 3-deep (consumed by phase2 only), meta 4-deep (combine(it-1) still
// reads meta[m_{it-1}]; slot (m+2)&3 = m_{it-2} last read by combine(it-2), done by B2(it-1)).
__global__ __launch_bounds__(512, 4) void fused_kernel(
    const float* __restrict__ x, const float* __restrict__ edge_attr,
    const float* __restrict__ edge_length, const int* __restrict__ edge_src,
    const int* __restrict__ edge_dst, const float* __restrict__ W1,
    const float* __restrict__ W2, const float* __restrict__ L0,
    const float* __restrict__ L1, float* __restrict__ out) {

    const int t = threadIdx.x;
    const int w = t >> 6;             // wave id 0..7
    const int lane = t & 63;
    const int q = w >> 1;             // W2 column chunk 0..3
    const int uh = w & 1;             // u-half
    const int qm = t & 15;            // MFMA m/n index
    const int quad = (t >> 4) & 3;    // lane quad within wave
    const int eL = t >> 4;            // phase2: edge within tile (0..31)
    const int uL = t & 15;            // phase2: raw u lane (0..15)
    const int uS = (uL + ((eL & 3) << 2)) & 15;   // swizzled u -> fewer xj read conflicts

    __shared__ __attribute__((aligned(16))) _Float16 lds_h16[ET * 72];   // h f16, stride 72
    __shared__ __attribute__((aligned(16))) float lds_cfT[3][16][CTS];   // coef planes 0..2, [u][e]
    __shared__ __attribute__((aligned(16))) float lds_cf3T[3][16][CTS];  // chunk3 coefs k=0..2, [u][e]
    __shared__ __attribute__((aligned(16))) float lds_xch[12 * XPS];     // term exchange
    __shared__ __attribute__((aligned(16))) float lds_w1t[64 * 8];       // W1^T [c][r]
    __shared__ __attribute__((aligned(16))) float l0[256], l1[256];      // L0, L1
    __shared__ __attribute__((aligned(16))) float lds_xj[3][ET * 64];    // 3-ring x[src], LINEAR stride 64
    __shared__ __attribute__((aligned(16))) float lds_ea[4][ET * 4];     // 4-ring edge_attr
    __shared__ __attribute__((aligned(16))) float lds_len[4][ET];        // 4-ring
    __shared__ __attribute__((aligned(16))) int   lds_dst[4][ET];        // 4-ring
    __shared__ __attribute__((aligned(16))) int   lds_srcb[4][ET];       // srcb[j%4] = src(tile j)

    // ---- persistent B fragments: W2 chunk `q`, u-half `uh`, pre-scaled f16 ----
    half8 bfr[8][2];
    {
        float scale = 0.0220970869f;                  // (1/sqrt(64)) * (1/sqrt(32))
        if (q == 1) scale *= 0.5773502692f;           // INV_SQRT3 folded
        const int kr = quad * 8;
        #pragma unroll
        for (int up = 0; up < 8; ++up) {
            const int col = q * 256 + (uh * 8 + up) * 16 + qm;
            #pragma unroll
            for (int kf = 0; kf < 2; ++kf) {
                half8 f;
                #pragma unroll
                for (int j = 0; j < 8; ++j) {
                    const int k = kf * 32 + kr + j;
                    f[j] = (_Float16)(W2[k * 1024 + col] * scale);
                }
                bfr[up][kf] = f;
            }
        }
    }
    // W1 -> LDS transposed [c][r]; L0/L1 -> LDS
    lds_w1t[(t & 63) * 8 + (t >> 6)] = W1[t];
    if (t < 256) l0[t] = L0[t];
    else         l1[t - 256] = L1[t - 256];

    // ---- prologue: srcb for tiles 0,1,2; stage tiles 0,1 ----
    int T = blockIdx.x;                 // tile being processed
    // tiles T, T+GRID, T+2*GRID all < 6250 for T < 512.
    if (w == 0 && lane < ET) gl_lds4(edge_src + T * ET + lane, &lds_srcb[0][0]);
    if (w == 1 && lane < ET) gl_lds4(edge_src + (T + GRID) * ET + lane, &lds_srcb[1][0]);
    if (w == 2 && lane < ET) gl_lds4(edge_src + (T + 2 * GRID) * ET + lane, &lds_srcb[2][0]);
    __syncthreads();   // srcb[0..2] visible; w1t/l0/l1 visible
    {
        const int e4 = (w << 2) + (lane >> 4);
        const int c4 = (lane & 15) * 4;
        gl_lds16(x + lds_srcb[0][e4] * 64 + c4, &lds_xj[0][w * 256]);
        gl_lds16(x + lds_srcb[1][e4] * 64 + c4, &lds_xj[1][w * 256]);
    }
    if (w == 0 && lane < ET) gl_lds16(edge_attr + 4 * (T * ET + lane), &lds_ea[0][0]);
    if (w == 1 && lane < ET) gl_lds4(edge_length + T * ET + lane, &lds_len[0][0]);
    if (w == 2 && lane < ET) gl_lds4(edge_dst + T * ET + lane, &lds_dst[0][0]);
    if (w == 3 && lane < ET) gl_lds16(edge_attr + 4 * ((T + GRID) * ET + lane), &lds_ea[1][0]);
    if (w == 4 && lane < ET) gl_lds4(edge_length + (T + GRID) * ET + lane, &lds_len[1][0]);
    if (w == 5 && lane < ET) gl_lds4(edge_dst + (T + GRID) * ET + lane, &lds_dst[1][0]);

    // ---- self-connection under the stage latency: shuffle matvec + atomics ----
    {
        const bool is0 = lane < 16;
        const int qq = lane - 16;
        const int v = is0 ? lane : qq / 3;
        const int k = is0 ? 0 : qq - 3 * v;
        const float* mat = is0 ? l0 : l1;
        for (int n = blockIdx.x * 8 + w; n < N_NODES; n += GRID * 8) {
            const float xv = x[n * 64 + lane];
            float s = 0.f;
            #pragma unroll
            for (int u = 0; u < 16; ++u) {
                const int sel = is0 ? u : 16 + 3 * u + k;
                s = fmaf(__shfl(xv, sel), mat[u * 16 + v], s);
            }
            atomicAdd(out + n * 64 + lane, 0.25f * s);   // 1/sqrt(MUL)
        }
    }
    __syncthreads();   // drains prologue stage: slots 0,1 ready

    int p = 0;   // xj ring index (it % 3)
    int m = 0;   // meta ring index (it % 4)
    while (true) {
        // ---- segA head: issue stage(T+2G) + srcb(T+3G) (zero registers held) ----
        const int T2 = T + 2 * GRID;
        if (T2 < NTILES) {
            const int p2 = (p < 1) ? p + 2 : p - 1;   // (p+2)%3
            const int m2 = (m + 2) & 3;
            {
                const int e4 = (w << 2) + (lane >> 4);
                const int src = lds_srcb[m2][e4];     // src(tile it+2), staged 1 iter ago
                gl_lds16(x + src * 64 + (lane & 15) * 4, &lds_xj[p2][w * 256]);
            }
            if (w == 0 && lane < ET) gl_lds16(edge_attr + 4 * (T2 * ET + lane), &lds_ea[m2][0]);
            if (w == 1 && lane < ET) gl_lds4(edge_length + T2 * ET + lane, &lds_len[m2][0]);
            if (w == 2 && lane < ET) gl_lds4(edge_dst + T2 * ET + lane, &lds_dst[m2][0]);
            if (w == 3 && lane < ET) {
                const int e3 = min((T + 3 * GRID) * ET + lane, N_EDGES - 1);
                gl_lds4(edge_src + e3, &lds_srcb[(m + 3) & 3][0]);
            }
        }

        // ---- phase 2: transposed coef (f32) + h16 from slot p / meta m ----
        {
            const float sh0 = lds_ea[m][eL * 4 + 0];
            const float s1x = lds_ea[m][eL * 4 + 1];
            const float s1y = lds_ea[m][eL * 4 + 2];
            const float s1z = lds_ea[m][eL * 4 + 3];
            const float* xr = &lds_xj[p][eL * 64];
            const float xj0v = xr[uS];
            const float x0 = xr[16 + 3 * uS];
            const float x1 = xr[17 + 3 * uS];
            const float x2 = xr[18 + 3 * uS];
            lds_cfT[0][uS][eL] = xj0v * sh0;
            lds_cfT[1][uS][eL] = fmaf(x0, s1x, fmaf(x1, s1y, x2 * s1z));
            lds_cfT[2][uS][eL] = xj0v;
            lds_cf3T[0][uS][eL] = x0 * sh0;
            lds_cf3T[1][uS][eL] = x1 * sh0;
            lds_cf3T[2][uS][eL] = x2 * sh0;
            // h = silu(radial @ W1 / sqrt(8)) for (e=eL, c = uS*4 .. +3), stored f16
            const int c0 = uS * 4;
            const float len = lds_len[m][eL];
            float rad[8];
            #pragma unroll
            for (int r = 0; r < 8; ++r) {
                const float d = len - 0.7142857143f * (float)r;
                rad[r] = __expf(-0.5f * d * d);
            }
            half4 hv;
            #pragma unroll
            for (int i = 0; i < 4; ++i) {
                const float4v wA = *(const float4v*)(&lds_w1t[(c0 + i) * 8]);
                const float4v wB = *(const float4v*)(&lds_w1t[(c0 + i) * 8 + 4]);
                float s = rad[0] * wA[0] + rad[1] * wA[1] + rad[2] * wA[2] + rad[3] * wA[3]
                        + rad[4] * wB[0] + rad[5] * wB[1] + rad[6] * wB[2] + rad[7] * wB[3];
                s *= 0.3535533906f;
                hv[i] = (_Float16)(s / (1.f + __expf(-s)));
            }
            *(half4*)(&lds_h16[eL * 72 + c0]) = hv;
        }

        wg_barrier();   // B1 (lgkm-only): cf/h16 visible; atomics + stage keep flying

        // ---- phase 3: unscaled-h MFMA -> au; contract with per-ROW coef (mt-split) ----
        if (q < 3) {
            #pragma unroll
            for (int mt = 0; mt < 2; ++mt) {
                const half8 a0 = *(const half8*)(&lds_h16[(mt * 16 + qm) * 72 + quad * 8]);
                const half8 a1 = *(const half8*)(&lds_h16[(mt * 16 + qm) * 72 + 32 + quad * 8]);
                float4v C = (float4v){0.f, 0.f, 0.f, 0.f};
                #pragma unroll
                for (int up = 0; up < 8; ++up) {
                    const int u = uh * 8 + up;
                    float4v au = __builtin_amdgcn_mfma_f32_16x16x32_f16(
                        a0, bfr[up][0], (float4v){0.f, 0.f, 0.f, 0.f}, 0, 0, 0);
                    au = __builtin_amdgcn_mfma_f32_16x16x32_f16(a1, bfr[up][1], au, 0, 0, 0);
                    const float4v cr = *(const float4v*)(&lds_cfT[q][u][mt * 16 + quad * 4]);
                    C += au * cr;     // per-row coef (rows quad*4+r)
                }
                float* xb = &lds_xch[(q * 2 + uh) * XPS];
                #pragma unroll
                for (int r = 0; r < 4; ++r)
                    xb[(mt * 16 + quad * 4 + r) * XRS + qm] = C[r];
            }
        } else {
            #pragma unroll
            for (int mt = 0; mt < 2; ++mt) {
                const half8 a0 = *(const half8*)(&lds_h16[(mt * 16 + qm) * 72 + quad * 8]);
                const half8 a1 = *(const half8*)(&lds_h16[(mt * 16 + qm) * 72 + 32 + quad * 8]);
                float4v C3[3];
                C3[0] = (float4v){0.f, 0.f, 0.f, 0.f};
                C3[1] = (float4v){0.f, 0.f, 0.f, 0.f};
                C3[2] = (float4v){0.f, 0.f, 0.f, 0.f};
                #pragma unroll
                for (int up = 0; up < 8; ++up) {
                    const int u = uh * 8 + up;
                    float4v au = __builtin_amdgcn_mfma_f32_16x16x32_f16(
                        a0, bfr[up][0], (float4v){0.f, 0.f, 0.f, 0.f}, 0, 0, 0);
                    au = __builtin_amdgcn_mfma_f32_16x16x32_f16(a1, bfr[up][1], au, 0, 0, 0);
                    #pragma unroll
                    for (int k = 0; k < 3; ++k) {
                        const float4v ck = *(const float4v*)(&lds_cf3T[k][u][mt * 16 + quad * 4]);
                        C3[k] += au * ck;
                    }
                }
                #pragma unroll
                for (int k = 0; k < 3; ++k) {
                    float* xb = &lds_xch[(6 + uh * 3 + k) * XPS];
                    #pragma unroll
                    for (int r = 0; r < 4; ++r)
                        xb[(mt * 16 + quad * 4 + r) * XRS + qm] = C3[k][r];
                }
            }
        }

        __syncthreads();   // B2: xch visible; stage(T+2G) + prev atomics drained
                           // (stage had phase2+phase3 of cover; atomics had segA+phase3)

        // ---- combine: 4 output elems per thread, ONE atomic each ----
        #pragma unroll
        for (int i = 0; i < 4; ++i) {
            const int idx = t + 512 * i;          // 2048 = 32 edges x 64 elems
            const int e = idx >> 6, j = idx & 63;
            float val;
            if (j < 16) {
                val = (lds_xch[0 * XPS + e * XRS + j] + lds_xch[1 * XPS + e * XRS + j])
                    + (lds_xch[2 * XPS + e * XRS + j] + lds_xch[3 * XPS + e * XRS + j]);
            } else {
                const int qj = j - 16, v = qj / 3, k = qj - 3 * v;
                const float s2 = lds_xch[4 * XPS + e * XRS + v] + lds_xch[5 * XPS + e * XRS + v];
                const float s3 = lds_xch[(6 + k) * XPS + e * XRS + v]
                               + lds_xch[(9 + k) * XPS + e * XRS + v];
                val = fmaf(s2, lds_ea[m][e * 4 + 1 + k], s3);
            }
            atomicAdd(out + lds_dst[m][e] * 64 + j, val);
        }

        T += GRID;
        if (T >= NTILES) break;
        p = (p < 2) ? p + 1 : 0;
        m = (m + 1) & 3;
        // next segA stages into xj[(p+2)%3] (phase2 done with it since it-1's B1)
        // and meta[(m+2)&3] (combine done with it since it-2, guaranteed by B2(it-1)).
    }
}

extern "C" void kernel_launch(void* const* d_in, const int* in_sizes, int n_in,
                              void* d_out, int out_size, void* d_ws, size_t ws_size,
                              hipStream_t stream) {
    const float* x           = (const float*)d_in[0];
    const float* edge_attr   = (const float*)d_in[1];
    const float* edge_length = (const float*)d_in[2];
    const int*   edge_src    = (const int*)d_in[3];
    const int*   edge_dst    = (const int*)d_in[4];
    const float* W1          = (const float*)d_in[5];
    const float* W2          = (const float*)d_in[6];
    const float* L0          = (const float*)d_in[7];
    const float* L1          = (const float*)d_in[8];
    float* out = (float*)d_out;

    hipMemsetAsync(out, 0, (size_t)N_NODES * 64 * sizeof(float), stream);
    fused_kernel<<<GRID, 512, 0, stream>>>(
        x, edge_attr, edge_length, edge_src, edge_dst, W1, W2, L0, L1, out);
}